// Round 13
// baseline (125.083 us; speedup 1.0000x reference)
//
#include <hip/hip_runtime.h>
#include <math.h>

#define BB 2
#define SS 2048
#define DIMM 1024
#define NHH 8
#define DHH 128
#define NSLOT 32   // <=5-tile chunks over 8 qq-groups (256 t-rows each), per bh

constexpr float GATE_CAP = 15.0f;
constexpr float B_EPS = 5e-5f;
constexpr float N_EPS = 1e-6f;
constexpr float LOG2E = 1.4426950408889634f;
constexpr float LN_KIS = -2.4260151319598084f;   // ln(1/sqrt(128))

typedef _Float16 f16x8 __attribute__((ext_vector_type(8)));
typedef __fp16  h16x2 __attribute__((ext_vector_type(2)));
typedef float f32x4 __attribute__((ext_vector_type(4)));

union U8 { f16x8 v; h16x2 h[4]; unsigned int u[4]; };

// slot tables: descending qq (5-tile chunks first => ids 0..255 all heavy)
__device__ __constant__ unsigned char SLOT2QQ[NSLOT] = {
    7,7,7,7,7,7,7, 6,6,6,6,6,6, 5,5,5,5,5, 4,4,4,4, 3,3,3,3, 2,2,2, 1,1, 0};
__device__ __constant__ unsigned char SLOT2ST0[NSLOT] = {
    0,5,10,15,20,25,30, 0,5,10,15,20,25, 0,5,10,15,20, 0,5,10,15, 0,4,8,12, 0,4,8, 0,4, 0};
__device__ __constant__ unsigned char SLOT2LEN[NSLOT] = {
    5,5,5,5,5,5,2, 5,5,5,5,5,3, 5,5,5,5,4, 5,5,5,5, 4,4,4,4, 4,4,4, 4,4, 4};
__device__ __constant__ unsigned char QQ2BASE[8] = {31,29,26,22,18,13,7,0};
__device__ __constant__ unsigned char QQ2NCH[8]  = {1,2,3,4,4,5,6,7};

__device__ inline unsigned short f2bf(float x) {
    unsigned u = __builtin_bit_cast(unsigned, x);
    unsigned r = (u + 0x7fff + ((u >> 16) & 1)) >> 16;   // RTNE
    return (unsigned short)r;
}
__device__ inline float bf2f(unsigned short s) {
    unsigned u = ((unsigned)s) << 16;
    return __builtin_bit_cast(float, u);
}

#define GLD_LDS16(gsrc, ldst)                                                   \
    __builtin_amdgcn_global_load_lds(                                           \
        (const __attribute__((address_space(1))) unsigned int*)(gsrc),          \
        (__attribute__((address_space(3))) unsigned int*)(ldst), 16, 0, 0)

// ---------------- Kernel 1: gate GEMV + k16 emit from staged LDS ----------------
__global__ __launch_bounds__(256) void gate_kernel(
    const float* __restrict__ q, const float* __restrict__ k, const float* __restrict__ v,
    const float* __restrict__ gw, const float* __restrict__ gb,
    float* __restrict__ i_pre, float* __restrict__ lfcs,
    unsigned short* __restrict__ k16)
{
    __shared__ __align__(16) float xs[2][8][1024];

    const int tid = threadIdx.x;
    const int lane = tid & 63;
    const int wv = tid >> 6;
    const int bs0 = blockIdx.x * 8;

    const float* srcs[3] = {q, k, v};

    auto stage = [&](int buf, int i) {
        const char* src = (const char*)(srcs[i] + (size_t)bs0 * DIMM);
        #pragma unroll
        for (int j = 0; j < 8; ++j) {
            GLD_LDS16(src + j * 4096 + wv * 1024 + lane * 16,
                      (char*)&xs[buf][j][0] + wv * 1024 + lane * 16);
        }
    };

    float acc[8][4];
    #pragma unroll
    for (int r = 0; r < 8; ++r)
        #pragma unroll
        for (int o = 0; o < 4; ++o) acc[r][o] = 0.f;

    stage(0, 0);

    for (int i = 0; i < 3; ++i) {
        const int cur = i & 1;
        const float* gwi = gw + (wv * 4) * 3 * DIMM + i * DIMM;
        float4 w4[4][4];
        #pragma unroll
        for (int step = 0; step < 4; ++step)
            #pragma unroll
            for (int o = 0; o < 4; ++o)
                w4[step][o] = *(const float4*)&gwi[o * 3 * DIMM + step * 256 + lane * 4];

        if (i < 2) {
            stage(cur ^ 1, i + 1);
            asm volatile("s_waitcnt vmcnt(8)" ::: "memory");
        } else {
            asm volatile("s_waitcnt vmcnt(0)" ::: "memory");
        }
        __builtin_amdgcn_s_barrier();
        __builtin_amdgcn_sched_barrier(0);

        #pragma unroll
        for (int step = 0; step < 4; ++step) {
            #pragma unroll
            for (int r = 0; r < 8; ++r) {
                const float4 xv = *(const float4*)&xs[cur][r][step * 256 + lane * 4];
                #pragma unroll
                for (int o = 0; o < 4; ++o)
                    acc[r][o] += xv.x * w4[step][o].x + xv.y * w4[step][o].y
                               + xv.z * w4[step][o].z + xv.w * w4[step][o].w;
            }
        }
        __builtin_amdgcn_s_barrier();
    }

    // ---- k16 emit: k slice resident in xs[1] ----
    #pragma unroll
    for (int it = 0; it < 8; ++it) {
        const int item = it * 256 + tid;
        const int r = item >> 8;
        const int dq = item & 255;
        const int hh = dq >> 5;
        const int dd4 = dq & 31;
        float4 kx = *(const float4*)&xs[1][r][dq * 4];
        h16x2 p0 = __builtin_amdgcn_cvt_pkrtz(kx.x, kx.y);
        h16x2 p1 = __builtin_amdgcn_cvt_pkrtz(kx.z, kx.w);
        uint2 wd;
        wd.x = __builtin_bit_cast(unsigned int, p0);
        wd.y = __builtin_bit_cast(unsigned int, p1);
        const int bs = bs0 + r;
        const int b = bs >> 11, s2 = bs & 2047;
        const size_t bh = (size_t)b * NHH + hh;
        *(uint2*)((char*)k16 + (bh * 2048 + s2) * 256 + ((dd4 * 8) ^ ((s2 & 7) << 4))) = wd;
    }

    #pragma unroll
    for (int r = 0; r < 8; ++r)
        #pragma unroll
        for (int o = 0; o < 4; ++o) {
            acc[r][o] += __shfl_xor(acc[r][o], 16);
            acc[r][o] += __shfl_xor(acc[r][o], 32);
        }

    float* scr = &xs[0][0][0];
    const int l16 = lane & 15;
    if (l16 == lane) {
        #pragma unroll
        for (int r = 0; r < 8; ++r) {
            float4 st = {acc[r][0], acc[r][1], acc[r][2], acc[r][3]};
            *(float4*)&scr[wv * 576 + l16 * 36 + r * 4] = st;
        }
    }
    __syncthreads();

    if (tid < 128) {
        const int row = tid & 7, o = tid >> 3;
        const float* base = &scr[(o >> 2) * 576 + row * 4 + (o & 3)];
        float s = 0.f;
        #pragma unroll
        for (int j = 0; j < 16; ++j) s += base[j * 36];
        float p = s + gb[o];
        p = GATE_CAP * tanhf(p / GATE_CAP);
        const int bs = bs0 + row;
        const int b = bs >> 11, s2 = bs & 2047;
        if (o < NHH) {
            i_pre[((size_t)b * NHH + o) * SS + s2] = p;
        } else {
            const int h = o - NHH;
            const float ls = (p >= 0.f) ? -log1pf(expf(-p)) : p - log1pf(expf(p));
            lfcs[((size_t)b * NHH + h) * SS + s2] = ls;
        }
    }
}

// ---------------- Kernel 2: V transpose (0..511) + scan (512..527) ----------------
__global__ __launch_bounds__(256) void vscan_kernel(
    const float* __restrict__ v, unsigned short* __restrict__ v16,
    const float* __restrict__ i_pre,
    float* __restrict__ lfcs, float* __restrict__ mstab, float* __restrict__ aa)
{
    const int id = blockIdx.x;
    const int tid = threadIdx.x;
    __shared__ float wt[4], wm[4];

    if (id < 512) {
        const int bh = id & 15;
        const int st = id >> 4;
        const int b = bh >> 3, h = bh & 7;
        const int d2 = (tid & 63) * 2;
        const int kb = (tid >> 6) & 1;
        const int gq = tid >> 7;
        const float* vp = v + ((size_t)b * SS + st * 64 + kb * 32) * DIMM + h * DHH + d2;
        char* base = (char*)v16 + ((size_t)bh * 32 + st) * 16384;
        #pragma unroll
        for (int gg = 0; gg < 2; ++gg) {
            const int g = gq * 2 + gg;
            float2 e[8];
            #pragma unroll
            for (int j = 0; j < 8; ++j) {
                const int s = 16 * (j >> 2) + 4 * g + (j & 3);
                e[j] = *(const float2*)&vp[(size_t)s * DIMM];
            }
            U8 u0, u1;
            u0.h[0] = __builtin_amdgcn_cvt_pkrtz(e[0].x, e[1].x);
            u0.h[1] = __builtin_amdgcn_cvt_pkrtz(e[2].x, e[3].x);
            u0.h[2] = __builtin_amdgcn_cvt_pkrtz(e[4].x, e[5].x);
            u0.h[3] = __builtin_amdgcn_cvt_pkrtz(e[6].x, e[7].x);
            u1.h[0] = __builtin_amdgcn_cvt_pkrtz(e[0].y, e[1].y);
            u1.h[1] = __builtin_amdgcn_cvt_pkrtz(e[2].y, e[3].y);
            u1.h[2] = __builtin_amdgcn_cvt_pkrtz(e[4].y, e[5].y);
            u1.h[3] = __builtin_amdgcn_cvt_pkrtz(e[6].y, e[7].y);
            const int p0 = kb * 64 + g * 16;
            *(f16x8*)(base + d2 * 128       + (p0 ^ ((d2 & 7) << 4)))       = u0.v;
            *(f16x8*)(base + (d2 + 1) * 128 + (p0 ^ (((d2 + 1) & 7) << 4))) = u1.v;
        }
        return;
    }

    const int bh = id - 512;
    const int lane = tid & 63, wv = tid >> 6;
    const size_t base = (size_t)bh * SS + tid * 8;

    float x[8];
    {
        float4 a0 = *(const float4*)&lfcs[base];
        float4 a1 = *(const float4*)&lfcs[base + 4];
        x[0] = a0.x; x[1] = a0.y; x[2] = a0.z; x[3] = a0.w;
        x[4] = a1.x; x[5] = a1.y; x[6] = a1.z; x[7] = a1.w;
    }
    #pragma unroll
    for (int i = 1; i < 8; ++i) x[i] += x[i - 1];

    const float tot = x[7];
    float inc = tot;
    #pragma unroll
    for (int off = 1; off < 64; off <<= 1) {
        float n = __shfl_up(inc, off);
        if (lane >= off) inc += n;
    }
    const float exc = inc - tot;

    if (lane == 63) wt[wv] = inc;
    __syncthreads();
    float wpre = 0.f;
    for (int w = 0; w < 4; ++w) if (w < wv) wpre += wt[w];
    const float off0 = exc + wpre;
    #pragma unroll
    for (int i = 0; i < 8; ++i) x[i] += off0;
    {
        float4 s0 = {x[0], x[1], x[2], x[3]}, s1 = {x[4], x[5], x[6], x[7]};
        *(float4*)&lfcs[base] = s0;
        *(float4*)&lfcs[base + 4] = s1;
    }

    float g[8];
    {
        float4 i0 = *(const float4*)&i_pre[base];
        float4 i1 = *(const float4*)&i_pre[base + 4];
        g[0] = i0.x - x[0]; g[1] = i0.y - x[1]; g[2] = i0.z - x[2]; g[3] = i0.w - x[3];
        g[4] = i1.x - x[4]; g[5] = i1.y - x[5]; g[6] = i1.z - x[6]; g[7] = i1.w - x[7];
        float4 s0 = {g[0] * LOG2E, g[1] * LOG2E, g[2] * LOG2E, g[3] * LOG2E};
        float4 s1 = {g[4] * LOG2E, g[5] * LOG2E, g[6] * LOG2E, g[7] * LOG2E};
        *(float4*)&aa[base] = s0;
        *(float4*)&aa[base + 4] = s1;
    }
    float mg[8];
    mg[0] = g[0];
    #pragma unroll
    for (int i = 1; i < 8; ++i) mg[i] = fmaxf(mg[i - 1], g[i]);

    float minc = mg[7];
    #pragma unroll
    for (int off = 1; off < 64; off <<= 1) {
        float n = __shfl_up(minc, off);
        if (lane >= off) minc = fmaxf(minc, n);
    }
    float mexc = __shfl_up(minc, 1);
    if (lane == 0) mexc = -1e30f;
    if (lane == 63) wm[wv] = minc;
    __syncthreads();
    float wmpre = -1e30f;
    for (int w = 0; w < 4; ++w) if (w < wv) wmpre = fmaxf(wmpre, wm[w]);
    const float pm = fmaxf(mexc, wmpre);
    float4 s0, s1;
    s0.x = x[0] + fmaxf(pm, mg[0]); s0.y = x[1] + fmaxf(pm, mg[1]);
    s0.z = x[2] + fmaxf(pm, mg[2]); s0.w = x[3] + fmaxf(pm, mg[3]);
    s1.x = x[4] + fmaxf(pm, mg[4]); s1.y = x[5] + fmaxf(pm, mg[5]);
    s1.z = x[6] + fmaxf(pm, mg[6]); s1.w = x[7] + fmaxf(pm, mg[7]);
    *(float4*)&mstab[base] = s0;
    *(float4*)&mstab[base + 4] = s1;
}

// ---------------- Kernel 3: MFMA mLSTM split-K (512 thr, 256 t-rows) ----------------
// __launch_bounds__(512, 2): 2 waves/SIMD -> ~256 regs/wave = 64 AGPR (oacc) + ~116 arch.
// (512,4) was the r10 disaster: 128-reg budget -> spill -> 1 GB scratch traffic.
__global__ __launch_bounds__(512, 2) void mlstm_splitk(
    const float* __restrict__ q,
    const unsigned short* __restrict__ k16, const unsigned short* __restrict__ v16,
    const float* __restrict__ lfcs, const float* __restrict__ aa,
    unsigned short* __restrict__ pnum, float* __restrict__ pden)
{
    __shared__ __align__(16) unsigned short kbuf[2][8192];
    __shared__ __align__(16) unsigned short vbuf[2][8192];

    const int tid = threadIdx.x;
    const int lane = tid & 63;
    const int wv = tid >> 6;          // 0..7
    const int g = lane >> 4;
    const int l16 = lane & 15;

    const int id = blockIdx.x;
    const int bh = id & 15;
    const int slot = id >> 4;         // 0..31
    const int qq = SLOT2QQ[slot];
    const int st0 = SLOT2ST0[slot];
    const int st1 = st0 + SLOT2LEN[slot] - 1;
    const int b = bh >> 3, h = bh & 7;
    const int tw0 = qq * 256 + 32 * wv;

    const size_t bhS = (size_t)bh * SS;
    const float* qp = q + (size_t)b * SS * DIMM + h * DHH;
    const char* kg = (const char*)k16 + (size_t)bh * 524288;
    const char* vg = (const char*)v16 + (size_t)bh * 524288;

    f16x8 qf[2][4];
    float cdec2[2];
    #pragma unroll
    for (int nt = 0; nt < 2; ++nt) {
        const int t = tw0 + 16 * nt + l16;
        cdec2[nt] = (lfcs[bhS + t] + LN_KIS) * LOG2E;
        const float* qrow = qp + (size_t)t * DIMM;
        #pragma unroll
        for (int kb = 0; kb < 4; ++kb) {
            float4 x0 = *(const float4*)&qrow[kb * 32 + g * 8];
            float4 x1 = *(const float4*)&qrow[kb * 32 + g * 8 + 4];
            U8 uu;
            uu.h[0] = __builtin_amdgcn_cvt_pkrtz(x0.x, x0.y);
            uu.h[1] = __builtin_amdgcn_cvt_pkrtz(x0.z, x0.w);
            uu.h[2] = __builtin_amdgcn_cvt_pkrtz(x1.x, x1.y);
            uu.h[3] = __builtin_amdgcn_cvt_pkrtz(x1.z, x1.w);
            qf[nt][kb] = uu.v;
        }
    }

    f32x4 oacc[2][8];
    #pragma unroll
    for (int nt = 0; nt < 2; ++nt)
        #pragma unroll
        for (int mt = 0; mt < 8; ++mt)
            oacc[nt][mt] = (f32x4){0.f, 0.f, 0.f, 0.f};
    float dpart[2] = {0.f, 0.f};

    // stage: 4 linear global_load_lds per wave (2 K + 2 V), 32KB total per tile
    auto stage = [&](int bi, int st) {
        const char* ksrc = kg + (size_t)st * 16384;
        const char* vsrc = vg + (size_t)st * 16384;
        #pragma unroll
        for (int j = 0; j < 2; ++j) {
            const int off = (j * 8 + wv) * 1024;
            GLD_LDS16(ksrc + off + lane * 16, (char*)&kbuf[bi][0] + off);
            GLD_LDS16(vsrc + off + lane * 16, (char*)&vbuf[bi][0] + off);
        }
    };

    stage(0, st0);

    for (int st = st0; st <= st1; ++st) {
        const int cur = (st - st0) & 1;
        const float* ap = aa + bhS + st * 64;
        f32x4 av[4];
        av[0] = *(const f32x4*)&ap[g * 4];
        av[1] = *(const f32x4*)&ap[16 + g * 4];
        av[2] = *(const f32x4*)&ap[32 + g * 4];
        av[3] = *(const f32x4*)&ap[48 + g * 4];

        if (st < st1) {
            stage(cur ^ 1, st + 1);
            asm volatile("s_waitcnt vmcnt(4)" ::: "memory");
        } else {
            asm volatile("s_waitcnt vmcnt(0)" ::: "memory");
        }
        __builtin_amdgcn_s_barrier();
        __builtin_amdgcn_sched_barrier(0);

        const int s0 = st * 64;
        const bool diag = (st >= 4 * qq);

        f32x4 stacc[2][4];
        #pragma unroll
        for (int nt = 0; nt < 2; ++nt)
            #pragma unroll
            for (int ct = 0; ct < 4; ++ct)
                stacc[nt][ct] = (f32x4){0.f, 0.f, 0.f, 0.f};

        f16x8 pf[2][2];

        #define QKT_PAIR(CT0)                                                            \
            __builtin_amdgcn_s_setprio(1);                                               \
            _Pragma("unroll")                                                            \
            for (int ct = CT0; ct < CT0 + 2; ++ct) {                                     \
                const int row = ct * 16 + l16;                                           \
                _Pragma("unroll")                                                        \
                for (int kb = 0; kb < 4; ++kb) {                                         \
                    f16x8 kf = *(const f16x8*)((const char*)&kbuf[cur][0] +              \
                                ((row * 256 + kb * 64 + g * 16) ^ ((row & 7) << 4)));    \
                    stacc[0][ct] = __builtin_amdgcn_mfma_f32_16x16x32_f16(kf, qf[0][kb], stacc[0][ct], 0, 0, 0); \
                    stacc[1][ct] = __builtin_amdgcn_mfma_f32_16x16x32_f16(kf, qf[1][kb], stacc[1][ct], 0, 0, 0); \
                }                                                                        \
            }                                                                            \
            __builtin_amdgcn_s_setprio(0);

        #define DECAY_PACK(KB, MASKED)                                                   \
            _Pragma("unroll")                                                            \
            for (int nt = 0; nt < 2; ++nt) {                                             \
                float dsum = 0.f;                                                        \
                const int t_idx = tw0 + nt * 16 + l16;                                   \
                _Pragma("unroll")                                                        \
                for (int ct = 2 * (KB); ct < 2 * (KB) + 2; ++ct) {                       \
                    _Pragma("unroll")                                                    \
                    for (int i = 0; i < 4; ++i) {                                        \
                        const float e = __builtin_amdgcn_exp2f(cdec2[nt] + av[ct][i]);   \
                        float val = stacc[nt][ct][i] * e;                                \
                        if (MASKED && (s0 + ct * 16 + g * 4 + i > t_idx)) val = 0.f;     \
                        dsum += val;                                                     \
                        stacc[nt][ct][i] = val;                                          \
                    }                                                                    \
                }                                                                        \
                dpart[nt] += dsum;                                                       \
                U8 uu;                                                                   \
                uu.h[0] = __builtin_amdgcn_cvt_pkrtz(stacc[nt][2*(KB)][0],   stacc[nt][2*(KB)][1]);   \
                uu.h[1] = __builtin_amdgcn_cvt_pkrtz(stacc[nt][2*(KB)][2],   stacc[nt][2*(KB)][3]);   \
                uu.h[2] = __builtin_amdgcn_cvt_pkrtz(stacc[nt][2*(KB)+1][0], stacc[nt][2*(KB)+1][1]); \
                uu.h[3] = __builtin_amdgcn_cvt_pkrtz(stacc[nt][2*(KB)+1][2], stacc[nt][2*(KB)+1][3]); \
                pf[nt][KB] = uu.v;                                                       \
            }

        #define PV_HALF(KB)                                                              \
            __builtin_amdgcn_s_setprio(1);                                               \
            _Pragma("unroll")                                                            \
            for (int mt = 0; mt < 8; ++mt) {                                             \
                const int dI = mt * 16 + l16;                                            \
                f16x8 vf = *(const f16x8*)((const char*)&vbuf[cur][0] +                  \
                            dI * 128 + (((KB) * 64 + g * 16) ^ ((dI & 7) << 4)));        \
                oacc[0][mt] = __builtin_amdgcn_mfma_f32_16x16x32_f16(vf, pf[0][KB], oacc[0][mt], 0, 0, 0); \
                oacc[1][mt] = __builtin_amdgcn_mfma_f32_16x16x32_f16(vf, pf[1][KB], oacc[1][mt], 0, 0, 0); \
            }                                                                            \
            __builtin_amdgcn_s_setprio(0);

        if (diag) {
            QKT_PAIR(0)
            DECAY_PACK(0, 1)
            QKT_PAIR(2)
            PV_HALF(0)
            DECAY_PACK(1, 1)
            PV_HALF(1)
        } else {
            QKT_PAIR(0)
            DECAY_PACK(0, 0)
            QKT_PAIR(2)
            PV_HALF(0)
            DECAY_PACK(1, 0)
            PV_HALF(1)
        }

        #undef QKT_PAIR
        #undef DECAY_PACK
        #undef PV_HALF

        __builtin_amdgcn_sched_barrier(0);
        __builtin_amdgcn_s_barrier();
    }

    // ---- epilogue: fragment-order partials (fully coalesced) ----
    const size_t cidx = (size_t)bh * NSLOT + slot;
    #pragma unroll
    for (int nt = 0; nt < 2; ++nt) {
        float den = dpart[nt];
        den += __shfl_xor(den, 16);
        den += __shfl_xor(den, 32);
        const int row = wv * 32 + nt * 16 + l16;
        if (g == 0) pden[cidx * 256 + row] = den;
        #pragma unroll
        for (int mt = 0; mt < 8; ++mt) {
            ushort4 pk;
            pk.x = f2bf(oacc[nt][mt][0]);
            pk.y = f2bf(oacc[nt][mt][1]);
            pk.z = f2bf(oacc[nt][mt][2]);
            pk.w = f2bf(oacc[nt][mt][3]);
            *(ushort4*)&pnum[((cidx * 128 + wv * 16 + nt * 8 + mt) << 8) + lane * 4] = pk;
        }
    }
}

// ---------------- Kernel 4: chunk reduction + denom + RMSNorm ----------------
__global__ __launch_bounds__(256) void reduce_kernel(
    const unsigned short* __restrict__ pnum, const float* __restrict__ pden,
    const float* __restrict__ mstab, const float* __restrict__ onw,
    float* __restrict__ out)
{
    const int id = blockIdx.x;          // 16 bh * 16 qhalf
    const int bh = id & 15;
    const int qh = id >> 4;             // 0..15 (128-row groups)
    const int qq = qh >> 1;
    const int half = qh & 1;
    const int b = bh >> 3, h = bh & 7;
    const int tid = threadIdx.x;
    const int lane = tid & 63;
    const int wv = tid >> 6;            // 0..3
    const int g = lane >> 4;
    const int l16 = lane & 15;

    const int nch = QQ2NCH[qq];
    const size_t cbase = (size_t)bh * NSLOT + QQ2BASE[qq];
    const int wvS = half * 4 + wv;      // fragment row-group 0..7 within slot

    f32x4 acc[2][8];
    #pragma unroll
    for (int nt = 0; nt < 2; ++nt)
        #pragma unroll
        for (int mt = 0; mt < 8; ++mt)
            acc[nt][mt] = (f32x4){0.f, 0.f, 0.f, 0.f};
    float den[2] = {0.f, 0.f};

    for (int c = 0; c < nch; ++c) {
        const size_t fb = (cbase + c) * 128 + wvS * 16;
        #pragma unroll
        for (int nt = 0; nt < 2; ++nt) {
            #pragma unroll
            for (int mt = 0; mt < 8; ++mt) {
                ushort4 t4 = *(const ushort4*)&pnum[((fb + nt * 8 + mt) << 8) + lane * 4];
                acc[nt][mt][0] += bf2f(t4.x);
                acc[nt][mt][1] += bf2f(t4.y);
                acc[nt][mt][2] += bf2f(t4.z);
                acc[nt][mt][3] += bf2f(t4.w);
            }
            den[nt] += pden[(cbase + c) * 256 + wvS * 32 + nt * 16 + l16];
        }
    }

    #pragma unroll
    for (int nt = 0; nt < 2; ++nt) {
        const int t = qq * 256 + wvS * 32 + nt * 16 + l16;
        const float m = mstab[(size_t)bh * SS + t];
        const float em = __expf(-m);
        const float dt = den[nt] * em;
        const float denf = fmaxf(fabsf(dt), em) + B_EPS;
        const float inv = em / denf;
        float ssq = 0.f;
        #pragma unroll
        for (int mt = 0; mt < 8; ++mt) {
            #pragma unroll
            for (int i = 0; i < 4; ++i) {
                acc[nt][mt][i] *= inv;
                ssq += acc[nt][mt][i] * acc[nt][mt][i];
            }
        }
        ssq += __shfl_xor(ssq, 16);
        ssq += __shfl_xor(ssq, 32);
        const float rms = rsqrtf(ssq * (1.0f / DHH) + N_EPS);

        float* orow = out + ((size_t)b * SS + t) * DIMM + h * DHH;
        #pragma unroll
        for (int mt = 0; mt < 8; ++mt) {
            float4 gn = *(const float4*)&onw[h * DHH + mt * 16 + g * 4];
            float4 o4;
            o4.x = acc[nt][mt][0] * rms * (1.f + gn.x);
            o4.y = acc[nt][mt][1] * rms * (1.f + gn.y);
            o4.z = acc[nt][mt][2] * rms * (1.f + gn.z);
            o4.w = acc[nt][mt][3] * rms * (1.f + gn.w);
            *(float4*)&orow[mt * 16 + g * 4] = o4;
        }
    }
}

extern "C" void kernel_launch(void* const* d_in, const int* in_sizes, int n_in,
                              void* d_out, int out_size, void* d_ws, size_t ws_size,
                              hipStream_t stream) {
    const float* q   = (const float*)d_in[0];
    const float* k   = (const float*)d_in[1];
    const float* v   = (const float*)d_in[2];
    const float* gw  = (const float*)d_in[3];
    const float* gb  = (const float*)d_in[4];
    const float* onw = (const float*)d_in[5];
    float* out = (float*)d_out;

    float* ws    = (float*)d_ws;
    float* i_pre = ws;                  // 32768 f32
    float* lfcs  = ws + 32768;          // 32768
    float* mm    = ws + 65536;          // 32768
    float* aa    = ws + 98304;          // 32768 (pre-scaled by log2 e)
    float* pden  = ws + 131072;         // 512*256 f32 = 131072 (ends at 1MB exactly)
    unsigned short* pnum = (unsigned short*)((char*)d_ws + 1048576);   // 512*64KB = 33554432 B
    unsigned short* k16  = (unsigned short*)((char*)d_ws + 34603008);  // 8388608 B
    unsigned short* v16  = (unsigned short*)((char*)d_ws + 42991616);  // 8388608 B -> end ~51 MB

    hipLaunchKernelGGL(gate_kernel, dim3(BB * SS / 8), dim3(256), 0, stream,
                       q, k, v, gw, gb, i_pre, lfcs, k16);
    hipLaunchKernelGGL(vscan_kernel, dim3(528), dim3(256), 0, stream,
                       v, v16, i_pre, lfcs, mm, aa);
    hipLaunchKernelGGL(mlstm_splitk, dim3(16 * NSLOT), dim3(512), 0, stream,
                       q, k16, v16, lfcs, aa, pnum, pden);
    hipLaunchKernelGGL(reduce_kernel, dim3(16 * 16), dim3(256), 0, stream,
                       pnum, pden, mm, onw, out);
}

// Round 14
// 74.163 us; speedup vs baseline: 1.6866x; 1.6866x over previous
//
#include <hip/hip_runtime.h>
#include <math.h>

#define BB 2
#define SS 2048
#define DIMM 1024
#define NHH 8
#define DHH 128
#define NSLOT 51   // 6x64-row-tile chunks, single-qq (128 t-rows), per bh

constexpr float GATE_CAP = 15.0f;
constexpr float B_EPS = 5e-5f;
constexpr float N_EPS = 1e-6f;
constexpr float LOG2E = 1.4426950408889634f;
constexpr float LN_KIS = -2.4260151319598084f;   // ln(1/sqrt(128))

typedef _Float16 f16x8 __attribute__((ext_vector_type(8)));
typedef __fp16  h16x2 __attribute__((ext_vector_type(2)));
typedef float f32x4 __attribute__((ext_vector_type(4)));

union U8 { f16x8 v; h16x2 h[4]; unsigned int u[4]; };

// slot tables: descending qq (long chunks dispatch first), chunk ascending within qq
__device__ __constant__ unsigned char SLOT2QQ[NSLOT] = {
    15,15,15,15,15,15, 14,14,14,14,14, 13,13,13,13,13, 12,12,12,12,12,
    11,11,11,11, 10,10,10,10, 9,9,9,9, 8,8,8, 7,7,7, 6,6,6,
    5,5, 4,4, 3,3, 2, 1, 0};
__device__ __constant__ unsigned char SLOT2CH[NSLOT] = {
    0,1,2,3,4,5, 0,1,2,3,4, 0,1,2,3,4, 0,1,2,3,4,
    0,1,2,3, 0,1,2,3, 0,1,2,3, 0,1,2, 0,1,2, 0,1,2,
    0,1, 0,1, 0,1, 0, 0, 0};
__device__ __constant__ unsigned char QQ2BASE[16] = {50,49,48,46,44,42,39,36,33,29,25,21,16,11,6,0};
__device__ __constant__ unsigned char QQ2NCH[16]  = {1,1,1,2,2,2,3,3,3,4,4,4,5,5,5,6};

__device__ inline unsigned short f2bf(float x) {
    unsigned u = __builtin_bit_cast(unsigned, x);
    unsigned r = (u + 0x7fff + ((u >> 16) & 1)) >> 16;   // RTNE
    return (unsigned short)r;
}
__device__ inline float bf2f(unsigned short s) {
    unsigned u = ((unsigned)s) << 16;
    return __builtin_bit_cast(float, u);
}

#define GLD_LDS16(gsrc, ldst)                                                   \
    __builtin_amdgcn_global_load_lds(                                           \
        (const __attribute__((address_space(1))) unsigned int*)(gsrc),          \
        (__attribute__((address_space(3))) unsigned int*)(ldst), 16, 0, 0)

// ---------------- Kernel 1: gate GEMV + k16 emit from staged LDS ----------------
__global__ __launch_bounds__(256) void gate_kernel(
    const float* __restrict__ q, const float* __restrict__ k, const float* __restrict__ v,
    const float* __restrict__ gw, const float* __restrict__ gb,
    float* __restrict__ i_pre, float* __restrict__ lfcs,
    unsigned short* __restrict__ k16)
{
    __shared__ __align__(16) float xs[2][8][1024];

    const int tid = threadIdx.x;
    const int lane = tid & 63;
    const int wv = tid >> 6;
    const int bs0 = blockIdx.x * 8;

    const float* srcs[3] = {q, k, v};

    auto stage = [&](int buf, int i) {
        const char* src = (const char*)(srcs[i] + (size_t)bs0 * DIMM);
        #pragma unroll
        for (int j = 0; j < 8; ++j) {
            GLD_LDS16(src + j * 4096 + wv * 1024 + lane * 16,
                      (char*)&xs[buf][j][0] + wv * 1024 + lane * 16);
        }
    };

    float acc[8][4];
    #pragma unroll
    for (int r = 0; r < 8; ++r)
        #pragma unroll
        for (int o = 0; o < 4; ++o) acc[r][o] = 0.f;

    stage(0, 0);

    for (int i = 0; i < 3; ++i) {
        const int cur = i & 1;
        const float* gwi = gw + (wv * 4) * 3 * DIMM + i * DIMM;
        float4 w4[4][4];
        #pragma unroll
        for (int step = 0; step < 4; ++step)
            #pragma unroll
            for (int o = 0; o < 4; ++o)
                w4[step][o] = *(const float4*)&gwi[o * 3 * DIMM + step * 256 + lane * 4];

        if (i < 2) {
            stage(cur ^ 1, i + 1);
            asm volatile("s_waitcnt vmcnt(8)" ::: "memory");
        } else {
            asm volatile("s_waitcnt vmcnt(0)" ::: "memory");
        }
        __builtin_amdgcn_s_barrier();
        __builtin_amdgcn_sched_barrier(0);

        #pragma unroll
        for (int step = 0; step < 4; ++step) {
            #pragma unroll
            for (int r = 0; r < 8; ++r) {
                const float4 xv = *(const float4*)&xs[cur][r][step * 256 + lane * 4];
                #pragma unroll
                for (int o = 0; o < 4; ++o)
                    acc[r][o] += xv.x * w4[step][o].x + xv.y * w4[step][o].y
                               + xv.z * w4[step][o].z + xv.w * w4[step][o].w;
            }
        }
        __builtin_amdgcn_s_barrier();
    }

    // ---- k16 emit: k slice resident in xs[1] ----
    #pragma unroll
    for (int it = 0; it < 8; ++it) {
        const int item = it * 256 + tid;
        const int r = item >> 8;
        const int dq = item & 255;
        const int hh = dq >> 5;
        const int dd4 = dq & 31;
        float4 kx = *(const float4*)&xs[1][r][dq * 4];
        h16x2 p0 = __builtin_amdgcn_cvt_pkrtz(kx.x, kx.y);
        h16x2 p1 = __builtin_amdgcn_cvt_pkrtz(kx.z, kx.w);
        uint2 wd;
        wd.x = __builtin_bit_cast(unsigned int, p0);
        wd.y = __builtin_bit_cast(unsigned int, p1);
        const int bs = bs0 + r;
        const int b = bs >> 11, s2 = bs & 2047;
        const size_t bh = (size_t)b * NHH + hh;
        *(uint2*)((char*)k16 + (bh * 2048 + s2) * 256 + ((dd4 * 8) ^ ((s2 & 7) << 4))) = wd;
    }

    #pragma unroll
    for (int r = 0; r < 8; ++r)
        #pragma unroll
        for (int o = 0; o < 4; ++o) {
            acc[r][o] += __shfl_xor(acc[r][o], 16);
            acc[r][o] += __shfl_xor(acc[r][o], 32);
        }

    float* scr = &xs[0][0][0];
    const int l16 = lane & 15;
    if (l16 == lane) {
        #pragma unroll
        for (int r = 0; r < 8; ++r) {
            float4 st = {acc[r][0], acc[r][1], acc[r][2], acc[r][3]};
            *(float4*)&scr[wv * 576 + l16 * 36 + r * 4] = st;
        }
    }
    __syncthreads();

    if (tid < 128) {
        const int row = tid & 7, o = tid >> 3;
        const float* base = &scr[(o >> 2) * 576 + row * 4 + (o & 3)];
        float s = 0.f;
        #pragma unroll
        for (int j = 0; j < 16; ++j) s += base[j * 36];
        float p = s + gb[o];
        p = GATE_CAP * tanhf(p / GATE_CAP);
        const int bs = bs0 + row;
        const int b = bs >> 11, s2 = bs & 2047;
        if (o < NHH) {
            i_pre[((size_t)b * NHH + o) * SS + s2] = p;
        } else {
            const int h = o - NHH;
            const float ls = (p >= 0.f) ? -log1pf(expf(-p)) : p - log1pf(expf(p));
            lfcs[((size_t)b * NHH + h) * SS + s2] = ls;
        }
    }
}

// ---------------- Kernel 2: V transpose (0..511) + scan (512..527) ----------------
// scan also emits colfac into aa: colfac[s] = exp(i[s] - lf[s] + P0(tile)), P0 = prefix
// at the 64-tile start; and lf0[bh][32] = P0 per tile (for mlstm's row factor).
__global__ __launch_bounds__(256) void vscan_kernel(
    const float* __restrict__ v, unsigned short* __restrict__ v16,
    const float* __restrict__ i_pre,
    float* __restrict__ lfcs, float* __restrict__ mstab, float* __restrict__ aa,
    float* __restrict__ lf0)
{
    const int id = blockIdx.x;
    const int tid = threadIdx.x;
    __shared__ float wt[4], wm[4];

    if (id < 512) {
        const int bh = id & 15;
        const int st = id >> 4;
        const int b = bh >> 3, h = bh & 7;
        const int d2 = (tid & 63) * 2;
        const int kb = (tid >> 6) & 1;
        const int gq = tid >> 7;
        const float* vp = v + ((size_t)b * SS + st * 64 + kb * 32) * DIMM + h * DHH + d2;
        char* base = (char*)v16 + ((size_t)bh * 32 + st) * 16384;
        #pragma unroll
        for (int gg = 0; gg < 2; ++gg) {
            const int g = gq * 2 + gg;
            float2 e[8];
            #pragma unroll
            for (int j = 0; j < 8; ++j) {
                const int s = 16 * (j >> 2) + 4 * g + (j & 3);
                e[j] = *(const float2*)&vp[(size_t)s * DIMM];
            }
            U8 u0, u1;
            u0.h[0] = __builtin_amdgcn_cvt_pkrtz(e[0].x, e[1].x);
            u0.h[1] = __builtin_amdgcn_cvt_pkrtz(e[2].x, e[3].x);
            u0.h[2] = __builtin_amdgcn_cvt_pkrtz(e[4].x, e[5].x);
            u0.h[3] = __builtin_amdgcn_cvt_pkrtz(e[6].x, e[7].x);
            u1.h[0] = __builtin_amdgcn_cvt_pkrtz(e[0].y, e[1].y);
            u1.h[1] = __builtin_amdgcn_cvt_pkrtz(e[2].y, e[3].y);
            u1.h[2] = __builtin_amdgcn_cvt_pkrtz(e[4].y, e[5].y);
            u1.h[3] = __builtin_amdgcn_cvt_pkrtz(e[6].y, e[7].y);
            const int p0 = kb * 64 + g * 16;
            *(f16x8*)(base + d2 * 128       + (p0 ^ ((d2 & 7) << 4)))       = u0.v;
            *(f16x8*)(base + (d2 + 1) * 128 + (p0 ^ (((d2 + 1) & 7) << 4))) = u1.v;
        }
        return;
    }

    const int bh = id - 512;
    const int lane = tid & 63, wv = tid >> 6;
    const size_t base = (size_t)bh * SS + tid * 8;

    float x[8];
    {
        float4 a0 = *(const float4*)&lfcs[base];
        float4 a1 = *(const float4*)&lfcs[base + 4];
        x[0] = a0.x; x[1] = a0.y; x[2] = a0.z; x[3] = a0.w;
        x[4] = a1.x; x[5] = a1.y; x[6] = a1.z; x[7] = a1.w;
    }
    #pragma unroll
    for (int i = 1; i < 8; ++i) x[i] += x[i - 1];

    const float tot = x[7];
    float inc = tot;
    #pragma unroll
    for (int off = 1; off < 64; off <<= 1) {
        float n = __shfl_up(inc, off);
        if (lane >= off) inc += n;
    }
    const float exc = inc - tot;

    if (lane == 63) wt[wv] = inc;
    __syncthreads();
    float wpre = 0.f;
    for (int w = 0; w < 4; ++w) if (w < wv) wpre += wt[w];
    const float off0 = exc + wpre;          // exclusive prefix before this thread's 8 elems
    #pragma unroll
    for (int i = 0; i < 8; ++i) x[i] += off0;
    {
        float4 s0 = {x[0], x[1], x[2], x[3]}, s1 = {x[4], x[5], x[6], x[7]};
        *(float4*)&lfcs[base] = s0;
        *(float4*)&lfcs[base + 4] = s1;
    }

    // per-64-tile reference prefix P0 (tile = 8 consecutive threads)
    const float p0t = __shfl(off0, lane & 56);
    if ((tid & 7) == 0) lf0[bh * 32 + (tid >> 3)] = off0;

    float g[8];
    {
        float4 i0 = *(const float4*)&i_pre[base];
        float4 i1 = *(const float4*)&i_pre[base + 4];
        g[0] = i0.x - x[0]; g[1] = i0.y - x[1]; g[2] = i0.z - x[2]; g[3] = i0.w - x[3];
        g[4] = i1.x - x[4]; g[5] = i1.y - x[5]; g[6] = i1.z - x[6]; g[7] = i1.w - x[7];
        // colfac = exp(i[s] - lf[s] + P0): bounded by exp(cap + within-tile decay) -- f32-safe
        float4 s0, s1;
        s0.x = __builtin_amdgcn_exp2f((g[0] + p0t) * LOG2E);
        s0.y = __builtin_amdgcn_exp2f((g[1] + p0t) * LOG2E);
        s0.z = __builtin_amdgcn_exp2f((g[2] + p0t) * LOG2E);
        s0.w = __builtin_amdgcn_exp2f((g[3] + p0t) * LOG2E);
        s1.x = __builtin_amdgcn_exp2f((g[4] + p0t) * LOG2E);
        s1.y = __builtin_amdgcn_exp2f((g[5] + p0t) * LOG2E);
        s1.z = __builtin_amdgcn_exp2f((g[6] + p0t) * LOG2E);
        s1.w = __builtin_amdgcn_exp2f((g[7] + p0t) * LOG2E);
        *(float4*)&aa[base] = s0;
        *(float4*)&aa[base + 4] = s1;
    }
    float mg[8];
    mg[0] = g[0];
    #pragma unroll
    for (int i = 1; i < 8; ++i) mg[i] = fmaxf(mg[i - 1], g[i]);

    float minc = mg[7];
    #pragma unroll
    for (int off = 1; off < 64; off <<= 1) {
        float n = __shfl_up(minc, off);
        if (lane >= off) minc = fmaxf(minc, n);
    }
    float mexc = __shfl_up(minc, 1);
    if (lane == 0) mexc = -1e30f;
    if (lane == 63) wm[wv] = minc;
    __syncthreads();
    float wmpre = -1e30f;
    for (int w = 0; w < 4; ++w) if (w < wv) wmpre = fmaxf(wmpre, wm[w]);
    const float pm = fmaxf(mexc, wmpre);
    float4 s0, s1;
    s0.x = x[0] + fmaxf(pm, mg[0]); s0.y = x[1] + fmaxf(pm, mg[1]);
    s0.z = x[2] + fmaxf(pm, mg[2]); s0.w = x[3] + fmaxf(pm, mg[3]);
    s1.x = x[4] + fmaxf(pm, mg[4]); s1.y = x[5] + fmaxf(pm, mg[5]);
    s1.z = x[6] + fmaxf(pm, mg[6]); s1.w = x[7] + fmaxf(pm, mg[7]);
    *(float4*)&mstab[base] = s0;
    *(float4*)&mstab[base + 4] = s1;
}

// ---------------- Kernel 3: MFMA mLSTM split-K (r9 structure; factored decay) ----------------
__global__ __launch_bounds__(256, 2) void mlstm_splitk(
    const float* __restrict__ q,
    const unsigned short* __restrict__ k16, const unsigned short* __restrict__ v16,
    const float* __restrict__ lfcs, const float* __restrict__ aa,
    const float* __restrict__ lf0,
    unsigned short* __restrict__ pnum, float* __restrict__ pden)
{
    __shared__ __align__(16) unsigned short kbuf[2][8192];
    __shared__ __align__(16) unsigned short vbuf[2][8192];

    const int tid = threadIdx.x;
    const int lane = tid & 63;
    const int wv = tid >> 6;
    const int g = lane >> 4;
    const int l16 = lane & 15;

    const int id = blockIdx.x;
    const int bh = id & 15;
    const int slot = id >> 4;           // 0..50
    const int qq = SLOT2QQ[slot];
    const int chunk = SLOT2CH[slot];
    const int b = bh >> 3, h = bh & 7;
    const int tw0 = qq * 128 + 32 * wv;

    const size_t bhS = (size_t)bh * SS;
    const float* qp = q + (size_t)b * SS * DIMM + h * DHH;
    const char* kg = (const char*)k16 + (size_t)bh * 524288;
    const char* vg = (const char*)v16 + (size_t)bh * 524288;

    f16x8 qf[2][4];
    float cdec2[2];
    #pragma unroll
    for (int nt = 0; nt < 2; ++nt) {
        const int t = tw0 + 16 * nt + l16;
        cdec2[nt] = (lfcs[bhS + t] + LN_KIS) * LOG2E;
        const float* qrow = qp + (size_t)t * DIMM;
        #pragma unroll
        for (int kb = 0; kb < 4; ++kb) {
            float4 x0 = *(const float4*)&qrow[kb * 32 + g * 8];
            float4 x1 = *(const float4*)&qrow[kb * 32 + g * 8 + 4];
            U8 uu;
            uu.h[0] = __builtin_amdgcn_cvt_pkrtz(x0.x, x0.y);
            uu.h[1] = __builtin_amdgcn_cvt_pkrtz(x0.z, x0.w);
            uu.h[2] = __builtin_amdgcn_cvt_pkrtz(x1.x, x1.y);
            uu.h[3] = __builtin_amdgcn_cvt_pkrtz(x1.z, x1.w);
            qf[nt][kb] = uu.v;
        }
    }

    f32x4 oacc[2][8];
    #pragma unroll
    for (int nt = 0; nt < 2; ++nt)
        #pragma unroll
        for (int mt = 0; mt < 8; ++mt)
            oacc[nt][mt] = (f32x4){0.f, 0.f, 0.f, 0.f};
    float dpart[2] = {0.f, 0.f};

    const int st0 = chunk * 6;
    const int st1m = 2 * qq + 1;
    const int st1 = (st0 + 5 < st1m) ? (st0 + 5) : st1m;

    auto stage = [&](int bi, int st) {
        const char* ksrc = kg + (size_t)st * 16384;
        const char* vsrc = vg + (size_t)st * 16384;
        #pragma unroll
        for (int j = 0; j < 4; ++j) {
            const int off = (j * 4 + wv) * 1024;
            GLD_LDS16(ksrc + off + lane * 16, (char*)&kbuf[bi][0] + off);
            GLD_LDS16(vsrc + off + lane * 16, (char*)&vbuf[bi][0] + off);
        }
    };

    stage(0, st0);

    for (int st = st0; st <= st1; ++st) {
        const int cur = (st - st0) & 1;
        // issue data loads for this tile BEFORE next-tile stage (vmcnt ordering)
        const float* ap = aa + bhS + st * 64;
        f32x4 av[4];
        av[0] = *(const f32x4*)&ap[g * 4];
        av[1] = *(const f32x4*)&ap[16 + g * 4];
        av[2] = *(const f32x4*)&ap[32 + g * 4];
        av[3] = *(const f32x4*)&ap[48 + g * 4];
        const float lf0t = lf0[bh * 32 + st];

        if (st < st1) {
            stage(cur ^ 1, st + 1);
            asm volatile("s_waitcnt vmcnt(8)" ::: "memory");
        } else {
            asm volatile("s_waitcnt vmcnt(0)" ::: "memory");
        }
        __builtin_amdgcn_s_barrier();
        __builtin_amdgcn_sched_barrier(0);

        const int s0 = st * 64;
        const bool diag = (st >= 2 * qq);
        // row factor: exp(lf[t] - P0 + ln_kis), <= kis (no overflow)
        const float lf0l2 = lf0t * LOG2E;
        float rowf[2];
        rowf[0] = __builtin_amdgcn_exp2f(cdec2[0] - lf0l2);
        rowf[1] = __builtin_amdgcn_exp2f(cdec2[1] - lf0l2);

        f32x4 stacc[2][4];
        #pragma unroll
        for (int nt = 0; nt < 2; ++nt)
            #pragma unroll
            for (int ct = 0; ct < 4; ++ct)
                stacc[nt][ct] = (f32x4){0.f, 0.f, 0.f, 0.f};

        f16x8 pf[2][2];

        #define QKT_PAIR(CT0)                                                            \
            __builtin_amdgcn_s_setprio(1);                                               \
            _Pragma("unroll")                                                            \
            for (int ct = CT0; ct < CT0 + 2; ++ct) {                                     \
                const int row = ct * 16 + l16;                                           \
                _Pragma("unroll")                                                        \
                for (int kb = 0; kb < 4; ++kb) {                                         \
                    f16x8 kf = *(const f16x8*)((const char*)&kbuf[cur][0] +              \
                                ((row * 256 + kb * 64 + g * 16) ^ ((row & 7) << 4)));    \
                    stacc[0][ct] = __builtin_amdgcn_mfma_f32_16x16x32_f16(kf, qf[0][kb], stacc[0][ct], 0, 0, 0); \
                    stacc[1][ct] = __builtin_amdgcn_mfma_f32_16x16x32_f16(kf, qf[1][kb], stacc[1][ct], 0, 0, 0); \
                }                                                                        \
            }                                                                            \
            __builtin_amdgcn_s_setprio(0);

        #define DECAY_PACK(KB)                                                           \
            _Pragma("unroll")                                                            \
            for (int nt = 0; nt < 2; ++nt) {                                             \
                float dsum = 0.f;                                                        \
                const int t_idx = tw0 + nt * 16 + l16;                                   \
                _Pragma("unroll")                                                        \
                for (int ct = 2 * (KB); ct < 2 * (KB) + 2; ++ct) {                       \
                    _Pragma("unroll")                                                    \
                    for (int i = 0; i < 4; ++i) {                                        \
                        float val = stacc[nt][ct][i] * av[ct][i] * rowf[nt];             \
                        if (diag && (s0 + ct * 16 + g * 4 + i > t_idx)) val = 0.f;       \
                        dsum += val;                                                     \
                        stacc[nt][ct][i] = val;                                          \
                    }                                                                    \
                }                                                                        \
                dpart[nt] += dsum;                                                       \
                U8 uu;                                                                   \
                uu.h[0] = __builtin_amdgcn_cvt_pkrtz(stacc[nt][2*(KB)][0],   stacc[nt][2*(KB)][1]);   \
                uu.h[1] = __builtin_amdgcn_cvt_pkrtz(stacc[nt][2*(KB)][2],   stacc[nt][2*(KB)][3]);   \
                uu.h[2] = __builtin_amdgcn_cvt_pkrtz(stacc[nt][2*(KB)+1][0], stacc[nt][2*(KB)+1][1]); \
                uu.h[3] = __builtin_amdgcn_cvt_pkrtz(stacc[nt][2*(KB)+1][2], stacc[nt][2*(KB)+1][3]); \
                pf[nt][KB] = uu.v;                                                       \
            }

        #define PV_HALF(KB)                                                              \
            __builtin_amdgcn_s_setprio(1);                                               \
            _Pragma("unroll")                                                            \
            for (int mt = 0; mt < 8; ++mt) {                                             \
                const int dI = mt * 16 + l16;                                            \
                f16x8 vf = *(const f16x8*)((const char*)&vbuf[cur][0] +                  \
                            dI * 128 + (((KB) * 64 + g * 16) ^ ((dI & 7) << 4)));        \
                oacc[0][mt] = __builtin_amdgcn_mfma_f32_16x16x32_f16(vf, pf[0][KB], oacc[0][mt], 0, 0, 0); \
                oacc[1][mt] = __builtin_amdgcn_mfma_f32_16x16x32_f16(vf, pf[1][KB], oacc[1][mt], 0, 0, 0); \
            }                                                                            \
            __builtin_amdgcn_s_setprio(0);

        QKT_PAIR(0)
        DECAY_PACK(0)
        QKT_PAIR(2)
        PV_HALF(0)
        DECAY_PACK(1)
        PV_HALF(1)

        #undef QKT_PAIR
        #undef DECAY_PACK
        #undef PV_HALF

        __builtin_amdgcn_sched_barrier(0);
        __builtin_amdgcn_s_barrier();
    }

    const size_t cidx = (size_t)bh * NSLOT + slot;
    #pragma unroll
    for (int nt = 0; nt < 2; ++nt) {
        float den = dpart[nt];
        den += __shfl_xor(den, 16);
        den += __shfl_xor(den, 32);
        const int row = wv * 32 + nt * 16 + l16;
        if (g == 0) pden[cidx * 128 + row] = den;
        #pragma unroll
        for (int mt = 0; mt < 8; ++mt) {
            ushort4 pk;
            pk.x = f2bf(oacc[nt][mt][0]);
            pk.y = f2bf(oacc[nt][mt][1]);
            pk.z = f2bf(oacc[nt][mt][2]);
            pk.w = f2bf(oacc[nt][mt][3]);
            *(ushort4*)&pnum[((cidx * 64 + wv * 16 + nt * 8 + mt) << 8) + lane * 4] = pk;
        }
    }
}

// ---------------- Kernel 4: chunk reduction + denom + RMSNorm ----------------
__global__ __launch_bounds__(256) void reduce_kernel(
    const unsigned short* __restrict__ pnum, const float* __restrict__ pden,
    const float* __restrict__ mstab, const float* __restrict__ onw,
    float* __restrict__ out)
{
    const int id = blockIdx.x;
    const int bh = id & 15;
    const int qq = id >> 4;
    const int b = bh >> 3, h = bh & 7;
    const int tid = threadIdx.x;
    const int lane = tid & 63;
    const int wv = tid >> 6;
    const int g = lane >> 4;
    const int l16 = lane & 15;

    const int nch = QQ2NCH[qq];
    const size_t cbase = (size_t)bh * NSLOT + QQ2BASE[qq];

    f32x4 acc[2][8];
    #pragma unroll
    for (int nt = 0; nt < 2; ++nt)
        #pragma unroll
        for (int mt = 0; mt < 8; ++mt)
            acc[nt][mt] = (f32x4){0.f, 0.f, 0.f, 0.f};
    float den[2] = {0.f, 0.f};

    for (int c = 0; c < nch; ++c) {
        const size_t fb = (cbase + c) * 64 + wv * 16;
        #pragma unroll
        for (int nt = 0; nt < 2; ++nt) {
            #pragma unroll
            for (int mt = 0; mt < 8; ++mt) {
                ushort4 t4 = *(const ushort4*)&pnum[((fb + nt * 8 + mt) << 8) + lane * 4];
                acc[nt][mt][0] += bf2f(t4.x);
                acc[nt][mt][1] += bf2f(t4.y);
                acc[nt][mt][2] += bf2f(t4.z);
                acc[nt][mt][3] += bf2f(t4.w);
            }
            den[nt] += pden[(cbase + c) * 128 + wv * 32 + nt * 16 + l16];
        }
    }

    #pragma unroll
    for (int nt = 0; nt < 2; ++nt) {
        const int t = qq * 128 + wv * 32 + nt * 16 + l16;
        const float m = mstab[(size_t)bh * SS + t];
        const float em = __expf(-m);
        const float dt = den[nt] * em;
        const float denf = fmaxf(fabsf(dt), em) + B_EPS;
        const float inv = em / denf;
        float ssq = 0.f;
        #pragma unroll
        for (int mt = 0; mt < 8; ++mt) {
            #pragma unroll
            for (int i = 0; i < 4; ++i) {
                acc[nt][mt][i] *= inv;
                ssq += acc[nt][mt][i] * acc[nt][mt][i];
            }
        }
        ssq += __shfl_xor(ssq, 16);
        ssq += __shfl_xor(ssq, 32);
        const float rms = rsqrtf(ssq * (1.0f / DHH) + N_EPS);

        float* orow = out + ((size_t)b * SS + t) * DIMM + h * DHH;
        #pragma unroll
        for (int mt = 0; mt < 8; ++mt) {
            float4 gn = *(const float4*)&onw[h * DHH + mt * 16 + g * 4];
            float4 o4;
            o4.x = acc[nt][mt][0] * rms * (1.f + gn.x);
            o4.y = acc[nt][mt][1] * rms * (1.f + gn.y);
            o4.z = acc[nt][mt][2] * rms * (1.f + gn.z);
            o4.w = acc[nt][mt][3] * rms * (1.f + gn.w);
            *(float4*)&orow[mt * 16 + g * 4] = o4;
        }
    }
}

extern "C" void kernel_launch(void* const* d_in, const int* in_sizes, int n_in,
                              void* d_out, int out_size, void* d_ws, size_t ws_size,
                              hipStream_t stream) {
    const float* q   = (const float*)d_in[0];
    const float* k   = (const float*)d_in[1];
    const float* v   = (const float*)d_in[2];
    const float* gw  = (const float*)d_in[3];
    const float* gb  = (const float*)d_in[4];
    const float* onw = (const float*)d_in[5];
    float* out = (float*)d_out;

    float* ws    = (float*)d_ws;
    float* i_pre = ws;                  // 32768 f32
    float* lfcs  = ws + 32768;          // 32768
    float* mm    = ws + 65536;          // 32768
    float* aa    = ws + 98304;          // 32768 (colfac values)
    float* pden  = ws + 131072;         // 816*128 f32 = 104448 -> ends 235520
    float* lf0   = ws + 235520;         // 16*32 f32
    unsigned short* pnum = (unsigned short*)((char*)d_ws + 1048576);   // 816*16KB
    unsigned short* k16  = (unsigned short*)((char*)d_ws + 29360128);  // 8388608 B
    unsigned short* v16  = (unsigned short*)((char*)d_ws + 37748736);  // 8388608 B

    hipLaunchKernelGGL(gate_kernel, dim3(BB * SS / 8), dim3(256), 0, stream,
                       q, k, v, gw, gb, i_pre, lfcs, k16);
    hipLaunchKernelGGL(vscan_kernel, dim3(528), dim3(256), 0, stream,
                       v, v16, i_pre, lfcs, mm, aa, lf0);
    hipLaunchKernelGGL(mlstm_splitk, dim3(16 * NSLOT), dim3(256), 0, stream,
                       q, k16, v16, lfcs, aa, lf0, pnum, pden);
    hipLaunchKernelGGL(reduce_kernel, dim3(16 * 16), dim3(256), 0, stream,
                       pnum, pden, mm, onw, out);
}